// Round 1
// 734.039 us; speedup vs baseline: 1.2592x; 1.2592x over previous
//
#include <hip/hip_runtime.h>

#define B_SZ  4096
#define T_LEN 1024
#define VOCAB 32000
#define HID   16

// tanh(x) = 1 - 2/(e^{2x}+1). Correct at both tails:
//   x->+inf: e->inf, 2/inf=0, t->1.  x->-inf: e->0, t->1-2=-1.
__device__ __forceinline__ float fast_tanh(float x) {
  float e = __expf(2.0f * x);
  return 1.0f - __fdividef(2.0f, e + 1.0f);
}

template<int CTRL>
__device__ __forceinline__ float dpp_f(float x) {
  int r = __builtin_amdgcn_update_dpp(0, __float_as_int(x), CTRL, 0xF, 0xF, false);
  return __int_as_float(r);
}

// DPP ctrl encodings (gfx9/CDNA):
//   quad_perm bcast k: k*0x55  (0x00, 0x55, 0xAA, 0xFF)
//   row_ror:8       = 0x128    (lane l -> l^8 within row of 16: quad q -> q^2)
//   row_mirror      = 0x140    (lane l -> 15-l within row: quad q -> q^3)
//   row_half_mirror = 0x141    (lane l -> l&~7 | 7-(l&7): quad q -> q^1)

// E2[v][i] = sum_j Wx_w[i][j] * embed[v][j] + Wx_b[i]
__global__ __launch_bounds__(256) void e2_kernel(
    const float* __restrict__ embed, const float* __restrict__ Wxw,
    const float* __restrict__ Wxb, float* __restrict__ E2) {
  int tid = blockIdx.x * 256 + threadIdx.x;   // 512000 threads
  int v = tid >> 4, i = tid & 15;
  const float4* er = (const float4*)(embed + (size_t)v * HID);
  const float4* wr = (const float4*)(Wxw + (size_t)i * HID);
  float acc = Wxb[i];
#pragma unroll
  for (int q = 0; q < 4; ++q) {
    float4 e4 = er[q], w4 = wr[q];
    acc = fmaf(w4.x, e4.x, acc);
    acc = fmaf(w4.y, e4.y, acc);
    acc = fmaf(w4.z, e4.z, acc);
    acc = fmaf(w4.w, e4.w, acc);
  }
  E2[tid] = acc;
}

// One chain per 16 lanes. Lane i holds ONLY h[i]; the per-step all-gather of
// h across the 16-lane row is done with pure-VALU DPP (no LDS pipe, no
// lgkmcnt on the critical path):
//   b_k = quad_perm bcast k  -> h[4q+k]        (quad-uniform values)
//   c_k = half_mirror(b_k)   -> h[4(q^1)+k]
//   d_k = ror8(b_k)          -> h[4(q^2)+k]
//   e_k = mirror(b_k)        -> h[4(q^3)+k]
// Lane pre-loads Wh row i in the matching XOR order: wp[t] = Wh[i][4*(q^t)..+3],
// giving 4 independent FMA partials (dep depth 4+2 instead of 16).
__global__ __launch_bounds__(256) void rnn_kernel(
    const int* __restrict__ seq, const float* __restrict__ E2,
    const float* __restrict__ Wh, float* __restrict__ hfin) {
  int tid = blockIdx.x * 256 + threadIdx.x;   // 65536 threads
  int b = tid >> 4, i = tid & 15;
  int q = (threadIdx.x >> 2) & 3;             // quad index within the 16-lane row

  float4 wp[4];
  const float* whrow = Wh + (size_t)i * HID;
#pragma unroll
  for (int t = 0; t < 4; ++t)
    wp[t] = *(const float4*)(whrow + 4 * (q ^ t));

  const int4*  seq4 = (const int4*)(seq + (size_t)b * T_LEN);
  const float* E2i  = E2 + i;

  // 3-deep index pipeline: idx1 = indices for group g+1 (loaded 2 iters ago,
  // covers ~900cy HBM latency on the streamed seq reads), idx2 = g+2.
  float xpA[4];
  int4 idx1, idx2;
  {
    int4 i0 = seq4[0];
    idx1 = seq4[1];
    idx2 = seq4[2];
    xpA[0] = E2i[(size_t)i0.x * HID];
    xpA[1] = E2i[(size_t)i0.y * HID];
    xpA[2] = E2i[(size_t)i0.z * HID];
    xpA[3] = E2i[(size_t)i0.w * HID];
  }

  float hcur = 0.0f;                          // this lane's h[i]; 0 at t=0

  for (int g = 0; g < T_LEN / 4; ++g) {
    int gn = (g + 3 < T_LEN / 4) ? (g + 3) : (T_LEN / 4 - 1);
    int4 idx3 = seq4[gn];                     // prefetch idx for group g+3
    float xpB[4];                             // prefetch xp for group g+1
    xpB[0] = E2i[(size_t)idx1.x * HID];
    xpB[1] = E2i[(size_t)idx1.y * HID];
    xpB[2] = E2i[(size_t)idx1.z * HID];
    xpB[3] = E2i[(size_t)idx1.w * HID];

#pragma unroll
    for (int s = 0; s < 4; ++s) {
      float b0 = dpp_f<0x00>(hcur);
      float b1 = dpp_f<0x55>(hcur);
      float b2 = dpp_f<0xAA>(hcur);
      float b3 = dpp_f<0xFF>(hcur);

      float c0 = dpp_f<0x141>(b0);            // q^1
      float c1 = dpp_f<0x141>(b1);
      float c2 = dpp_f<0x141>(b2);
      float c3 = dpp_f<0x141>(b3);

      float d0 = dpp_f<0x128>(b0);            // q^2
      float d1 = dpp_f<0x128>(b1);
      float d2 = dpp_f<0x128>(b2);
      float d3 = dpp_f<0x128>(b3);

      float e0 = dpp_f<0x140>(b0);            // q^3
      float e1 = dpp_f<0x140>(b1);
      float e2 = dpp_f<0x140>(b2);
      float e3 = dpp_f<0x140>(b3);

      float p0 = fmaf(wp[0].x, b0, xpA[s]);
      p0 = fmaf(wp[0].y, b1, p0);
      p0 = fmaf(wp[0].z, b2, p0);
      p0 = fmaf(wp[0].w, b3, p0);

      float p1 = wp[1].x * c0;
      p1 = fmaf(wp[1].y, c1, p1);
      p1 = fmaf(wp[1].z, c2, p1);
      p1 = fmaf(wp[1].w, c3, p1);

      float p2 = wp[2].x * d0;
      p2 = fmaf(wp[2].y, d1, p2);
      p2 = fmaf(wp[2].z, d2, p2);
      p2 = fmaf(wp[2].w, d3, p2);

      float p3 = wp[3].x * e0;
      p3 = fmaf(wp[3].y, e1, p3);
      p3 = fmaf(wp[3].z, e2, p3);
      p3 = fmaf(wp[3].w, e3, p3);

      hcur = fast_tanh((p0 + p1) + (p2 + p3));
    }

#pragma unroll
    for (int s = 0; s < 4; ++s) xpA[s] = xpB[s];
    idx1 = idx2;
    idx2 = idx3;
  }

  hfin[(size_t)b * HID + i] = hcur;           // lane i owns h[i]
}

// out[b][v] = sum_i hfin[b][i]*out_w[v][i] + out_b[v]
// Lane owns 4 consecutive v; wave covers 256 v; 16 b-rows per wave;
// 1-deep software pipeline on the broadcast h-row loads.
__global__ __launch_bounds__(256) void out_gemm(
    const float* __restrict__ hfin, const float* __restrict__ outw,
    const float* __restrict__ outb, float* __restrict__ out) {
  int lane = threadIdx.x & 63;
  int wv   = threadIdx.x >> 6;
  int v0 = blockIdx.x * 256 + lane * 4;
  int b0 = blockIdx.y * 64 + wv * 16;

  float w[4][16];
#pragma unroll
  for (int c = 0; c < 4; ++c) {
    const float4* wr = (const float4*)(outw + (size_t)(v0 + c) * HID);
#pragma unroll
    for (int qq = 0; qq < 4; ++qq) {
      float4 t = wr[qq];
      w[c][4*qq+0] = t.x; w[c][4*qq+1] = t.y; w[c][4*qq+2] = t.z; w[c][4*qq+3] = t.w;
    }
  }
  float4 ob = *(const float4*)(outb + v0);

  const float4* hr = (const float4*)(hfin + (size_t)b0 * HID);
  float4 ha[4], hb[4];
#pragma unroll
  for (int qq = 0; qq < 4; ++qq) ha[qq] = hr[qq];

  for (int r = 0; r < 16; ++r) {
    int rn = (r + 1 < 16) ? r + 1 : r;
#pragma unroll
    for (int qq = 0; qq < 4; ++qq) hb[qq] = hr[rn * 4 + qq];

    float hv[16];
#pragma unroll
    for (int qq = 0; qq < 4; ++qq) {
      hv[4*qq+0] = ha[qq].x; hv[4*qq+1] = ha[qq].y;
      hv[4*qq+2] = ha[qq].z; hv[4*qq+3] = ha[qq].w;
    }
    float4 acc = ob;
#pragma unroll
    for (int k = 0; k < 16; ++k) {
      acc.x = fmaf(w[0][k], hv[k], acc.x);
      acc.y = fmaf(w[1][k], hv[k], acc.y);
      acc.z = fmaf(w[2][k], hv[k], acc.z);
      acc.w = fmaf(w[3][k], hv[k], acc.w);
    }
    *(float4*)(out + (size_t)(b0 + r) * VOCAB + v0) = acc;

#pragma unroll
    for (int qq = 0; qq < 4; ++qq) ha[qq] = hb[qq];
  }
}

extern "C" void kernel_launch(void* const* d_in, const int* in_sizes, int n_in,
                              void* d_out, int out_size, void* d_ws, size_t ws_size,
                              hipStream_t stream) {
  const int*   seq   = (const int*)  d_in[0];
  const float* embed = (const float*)d_in[1];
  const float* Wh    = (const float*)d_in[2];
  const float* Wxw   = (const float*)d_in[3];
  const float* Wxb   = (const float*)d_in[4];
  const float* outw  = (const float*)d_in[5];
  const float* outb  = (const float*)d_in[6];
  float* out  = (float*)d_out;

  float* E2   = (float*)d_ws;                        // 32000*16 fp32 = 2.048 MB
  float* hfin = (float*)d_ws + (size_t)VOCAB * HID;  // 4096*16 fp32 = 256 KB

  e2_kernel<<<VOCAB * HID / 256, 256, 0, stream>>>(embed, Wxw, Wxb, E2);
  rnn_kernel<<<B_SZ * HID / 256, 256, 0, stream>>>(seq, E2, Wh, hfin);
  dim3 grid(VOCAB / 256, B_SZ / 64);
  out_gemm<<<grid, dim3(256), 0, stream>>>(hfin, outw, outb, out);
}